// Round 3
// baseline (8384.074 us; speedup 1.0000x reference)
//
#include <hip/hip_runtime.h>
#include <hip/hip_bf16.h>

// GRU sequence: B=64, T=512, LATENT=512, HIDDEN=1024. fp32 in/out, bf16 MFMA.
//
//   K0: convert W_ih fp32->bf16 (xproj B operand, read repeatedly)
//   K1: xproj = z @ W_ih^T + b_ih  (32768x3072x512 bf16 MFMA) -> XP bf16 in ws
//   K2: init (zero h0 + barrier counters)
//   K3: gru_persistent — ALL 512 timesteps in one kernel.
//       256 blocks x 256 thr = 1 block/CU (LDS 110.8 KB forces occupancy 1;
//       grid == #CUs => co-residency guaranteed => hand-rolled barrier safe).
//       4 independent sync groups (16 batch rows each) x 64 col-blocks.
//       Whh slice (48x1024 bf16 = 96 KB) persistent in swizzled LDS.
//       h fp32 carried in registers (thread owns its (m,j) across all t).

#define B_   64
#define T_   512
#define LAT_ 512
#define HID_ 1024
#define G3_  3072

typedef __bf16  bf8  __attribute__((ext_vector_type(8)));
typedef float   f4   __attribute__((ext_vector_type(4)));
typedef short   s8v  __attribute__((ext_vector_type(8)));
typedef short   s4v  __attribute__((ext_vector_type(4)));

__device__ __forceinline__ bf8 ldb8(const short* p) {
    s8v v = *(const s8v*)p;
    return __builtin_bit_cast(bf8, v);
}
__device__ __forceinline__ float b2f(short s) {
    return __bfloat162float(*(__hip_bfloat16*)&s);
}
__device__ __forceinline__ short f2b(float f) {
    __hip_bfloat16 h = __float2bfloat16(f);
    return *(short*)&h;
}

// ---------------------------------------------------------------------------
// K0: fp32 -> bf16 elementwise
// ---------------------------------------------------------------------------
__global__ __launch_bounds__(256) void cvt_f2b_kernel(
    const float* __restrict__ in, short* __restrict__ out, int n)
{
    int i = (blockIdx.x * 256 + threadIdx.x) * 4;
    if (i + 3 < n) {
        f4 v = *(const f4*)(in + i);
        s4v r;
        r.x = f2b(v.x); r.y = f2b(v.y); r.z = f2b(v.z); r.w = f2b(v.w);
        *(s4v*)(out + i) = r;
    }
}

// ---------------------------------------------------------------------------
// K1: XP[r,g] = sum_k Z[r,k]*Wih[g,k] + bih[g]   (proven in R2)
// ---------------------------------------------------------------------------
__global__ __launch_bounds__(256) void xproj_kernel(
    const float* __restrict__ Z,     // (32768, 512) fp32
    const short* __restrict__ Wih,   // (3072, 512) bf16
    const float* __restrict__ bih,   // (3072) fp32
    short* __restrict__ XP)          // (32768, 3072) bf16
{
    __shared__ short As[128 * 32];
    __shared__ short Bs[128 * 32];

    const int tid  = threadIdx.x;
    const int lane = tid & 63;
    const int wid  = tid >> 6;
    const int wm   = wid & 1;
    const int wn   = wid >> 1;
    const int lrow = lane & 15;
    const int quad = lane >> 4;

    const long arow0 = (long)blockIdx.y * 128;
    const long brow0 = (long)blockIdx.x * 128;

    f4 acc[4][4];
    const f4 zf = {0.f, 0.f, 0.f, 0.f};
#pragma unroll
    for (int i = 0; i < 4; i++)
#pragma unroll
        for (int j = 0; j < 4; j++) acc[i][j] = zf;

    for (int k0 = 0; k0 < LAT_; k0 += 32) {
#pragma unroll
        for (int i = 0; i < 4; i++) {
            int c   = tid + 256 * i;
            int row = c >> 3;
            int kc  = (c & 7) * 4;
            f4 v = *(const f4*)(Z + (arow0 + row) * LAT_ + k0 + kc);
            s4v r;
            r.x = f2b(v.x); r.y = f2b(v.y); r.z = f2b(v.z); r.w = f2b(v.w);
            *(s4v*)(As + row * 32 + kc) = r;
        }
#pragma unroll
        for (int i = 0; i < 2; i++) {
            int c   = tid + 256 * i;
            int row = c >> 2;
            int kc  = (c & 3) * 8;
            *(s8v*)(Bs + row * 32 + kc) = *(const s8v*)(Wih + (brow0 + row) * LAT_ + k0 + kc);
        }
        __syncthreads();

        bf8 af[4], bfr[4];
#pragma unroll
        for (int mf = 0; mf < 4; mf++)
            af[mf] = ldb8(As + (wm * 64 + mf * 16 + lrow) * 32 + quad * 8);
#pragma unroll
        for (int nf = 0; nf < 4; nf++)
            bfr[nf] = ldb8(Bs + (wn * 64 + nf * 16 + lrow) * 32 + quad * 8);

#pragma unroll
        for (int mf = 0; mf < 4; mf++)
#pragma unroll
            for (int nf = 0; nf < 4; nf++)
                acc[mf][nf] = __builtin_amdgcn_mfma_f32_16x16x32_bf16(
                    af[mf], bfr[nf], acc[mf][nf], 0, 0, 0);
        __syncthreads();
    }

#pragma unroll
    for (int nf = 0; nf < 4; nf++) {
        int gc = (int)brow0 + wn * 64 + nf * 16 + lrow;
        float bias = bih[gc];
#pragma unroll
        for (int mf = 0; mf < 4; mf++) {
#pragma unroll
            for (int r = 0; r < 4; r++) {
                long gr = arow0 + wm * 64 + mf * 16 + quad * 4 + r;
                XP[gr * G3_ + gc] = f2b(acc[mf][nf][r] + bias);
            }
        }
    }
}

// ---------------------------------------------------------------------------
// K2: zero h0 (65536 bf16) and barrier counters (64 ints)
// ---------------------------------------------------------------------------
__global__ __launch_bounds__(256) void init_kernel(short* h0, int* ctrs) {
    int i = blockIdx.x * 256 + threadIdx.x;   // grid 256 x 256 = 65536
    h0[i] = 0;
    if (i < 64) ctrs[i] = 0;
}

// ---------------------------------------------------------------------------
// K3: persistent GRU recurrence.
//   group = blockIdx.x>>6 (batch rows 16*grp..+16), col-block cb = blockIdx.x&63
//   (h-cols 16*cb..+16, all 3 gates). Whh slice 48x1024 bf16 in LDS, XOR-
//   swizzled 16B chunks (2-way conflict max on ds_read_b128).
//   Waves split K=1024 4 ways; 12.25 KB LDS reduce; fused gates; per-group
//   monotonic atomic barrier per step.
// ---------------------------------------------------------------------------
__global__ __launch_bounds__(256) void gru_persistent(
    const float* __restrict__ Whh,   // (3072,1024) fp32
    const short* __restrict__ XP,    // (32768,3072) bf16
    const float* __restrict__ bhh,   // (3072) fp32
    short* __restrict__ h0,          // (64,1024) bf16 (zeroed)
    short* __restrict__ h1,          // (64,1024) bf16
    float* __restrict__ Out,         // (64,512,1024) fp32
    int*  __restrict__ ctrs)         // 4 groups, stride 16 ints
{
    extern __shared__ char smem[];
    short* Bs  = (short*)smem;                     // 48*1024 bf16 = 96 KB
    float* red = (float*)(smem + 48 * 1024 * 2);   // [4][16][49] = 12.25 KB

    const int tid  = threadIdx.x;
    const int lane = tid & 63;
    const int w    = tid >> 6;
    const int lrow = lane & 15;
    const int quad = lane >> 4;

    const int grp  = blockIdx.x >> 6;
    const int cb   = blockIdx.x & 63;
    const int c0   = cb * 16;
    const int row0 = grp * 16;
    int* ctr = ctrs + grp * 16;

    // ---- stage Whh slice fp32->bf16 into swizzled LDS (once) ----
    // LDS row r (= g*16 + cc, global row g*1024 + c0 + cc); 16B chunk c of row
    // stored at chunk index (c ^ (r&7)) -> lanes 0..15 hit 2-way max on b128.
    for (int ch = tid; ch < 48 * 128; ch += 256) {
        int r  = ch >> 7;
        int c  = ch & 127;
        int g  = r >> 4;
        int cc = r & 15;
        const float* src = Whh + (long)(g * HID_ + c0 + cc) * HID_ + c * 8;
        s8v o;
#pragma unroll
        for (int i = 0; i < 8; i++) o[i] = f2b(src[i]);
        *(s8v*)(Bs + r * 1024 + ((c ^ (r & 7)) * 8)) = o;
    }

    // per-thread persistent fp32 h: thread -> (m = tid>>4, j = tid&15)
    const int em = tid >> 4;
    const int ej = tid & 15;
    float hfp = 0.f;

    const float br = bhh[c0 + ej];
    const float bz = bhh[HID_ + c0 + ej];
    const float bn = bhh[2 * HID_ + c0 + ej];

    __syncthreads();

    const int kbase = w * 256;
    const f4 zf = {0.f, 0.f, 0.f, 0.f};

    for (int t = 0; t < T_; t++) {
        const short* hc = (t & 1) ? h1 : h0;
        short*       hn = (t & 1) ? h0 : h1;

        // XP prefetch (consumed after reduce)
        const short* xrow = XP + ((long)(row0 + em) * T_ + t) * G3_;
        short xrs = xrow[c0 + ej];
        short xzs = xrow[HID_ + c0 + ej];
        short xns = xrow[2 * HID_ + c0 + ej];

        // MFMA: A = h rows [row0,row0+16), wave K-slice 256; B from LDS
        f4 acc[3] = {zf, zf, zf};
        for (int kk = 0; kk < 256; kk += 32) {
            int k = kbase + kk + quad * 8;
            bf8 a = ldb8(hc + (row0 + lrow) * HID_ + k);
#pragma unroll
            for (int g = 0; g < 3; g++) {
                int r = g * 16 + lrow;
                bf8 b = ldb8(Bs + r * 1024 + (((k >> 3) ^ (r & 7)) * 8));
                acc[g] = __builtin_amdgcn_mfma_f32_16x16x32_bf16(a, b, acc[g], 0, 0, 0);
            }
        }

        // partials: D row (batch) = quad*4+reg, col = lrow
#pragma unroll
        for (int g = 0; g < 3; g++)
#pragma unroll
            for (int r4 = 0; r4 < 4; r4++)
                red[w * 784 + (quad * 4 + r4) * 49 + g * 16 + lrow] = acc[g][r4];
        __syncthreads();

        // reduce over 4 waves + gates
        float ghr = br, ghz = bz, ghn = bn;
#pragma unroll
        for (int ww = 0; ww < 4; ww++) {
            const float* rr = red + ww * 784 + em * 49;
            ghr += rr[ej];
            ghz += rr[16 + ej];
            ghn += rr[32 + ej];
        }
        float xr = b2f(xrs), xz = b2f(xzs), xn = b2f(xns);
        float rg = 1.f / (1.f + __expf(-(xr + ghr)));
        float ug = 1.f / (1.f + __expf(-(xz + ghz)));
        float ng = tanhf(xn + rg * ghn);
        hfp = (1.f - ug) * ng + ug * hfp;

        hn[(row0 + em) * HID_ + c0 + ej] = f2b(hfp);
        Out[((long)(row0 + em) * T_ + t) * HID_ + c0 + ej] = hfp;

        __syncthreads();   // red reuse + all h stores issued (drained at barrier)
        if (t < T_ - 1) {
            if (tid == 0) {
                // release: drains this XCD L2; acquire: invalidates for fresh h
                __hip_atomic_fetch_add(ctr, 1, __ATOMIC_RELEASE, __HIP_MEMORY_SCOPE_AGENT);
                int target = 64 * (t + 1);
                while (__hip_atomic_load(ctr, __ATOMIC_ACQUIRE, __HIP_MEMORY_SCOPE_AGENT) < target)
                    __builtin_amdgcn_s_sleep(1);
            }
            __syncthreads();
        }
    }
}

extern "C" void kernel_launch(void* const* d_in, const int* in_sizes, int n_in,
                              void* d_out, int out_size, void* d_ws, size_t ws_size,
                              hipStream_t stream) {
    const float* Z   = (const float*)d_in[0];
    const float* Wih = (const float*)d_in[1];
    const float* Whh = (const float*)d_in[2];
    const float* bih = (const float*)d_in[3];
    const float* bhh = (const float*)d_in[4];
    float* out = (float*)d_out;

    char* ws = (char*)d_ws;
    size_t off = 0;
    short* XP    = (short*)(ws + off); off += (size_t)B_ * T_ * G3_ * 2;   // 201.3 MB
    short* Wihbf = (short*)(ws + off); off += (size_t)G3_ * LAT_ * 2;      // 3.1 MB
    short* h0    = (short*)(ws + off); off += (size_t)B_ * HID_ * 2;
    short* h1    = (short*)(ws + off); off += (size_t)B_ * HID_ * 2;
    int*   ctrs  = (int*)(ws + off);   off += 64 * sizeof(int);

    static int lds_attr_set = 0;
    const int LDS_BYTES = 48 * 1024 * 2 + 4 * 784 * 4;   // 110848
    if (!lds_attr_set) {
        hipFuncSetAttribute((const void*)gru_persistent,
                            hipFuncAttributeMaxDynamicSharedMemorySize, LDS_BYTES);
        lds_attr_set = 1;
    }

    cvt_f2b_kernel<<<(G3_ * LAT_) / 1024, 256, 0, stream>>>(Wih, Wihbf, G3_ * LAT_);
    xproj_kernel<<<dim3(24, 256), 256, 0, stream>>>(Z, Wihbf, bih, XP);
    init_kernel<<<256, 256, 0, stream>>>(h0, ctrs);
    gru_persistent<<<256, 256, LDS_BYTES, stream>>>(Whh, XP, bhh, h0, h1, out, ctrs);
}